// Round 6
// baseline (373.284 us; speedup 1.0000x reference)
//
#include <hip/hip_runtime.h>

typedef unsigned int u32;
typedef unsigned short u16;
typedef float f32x4 __attribute__((ext_vector_type(4)));
typedef __bf16 bf16x8 __attribute__((ext_vector_type(8)));

#define BATCH 128
#define NIN   1024
#define DIN   256
#define NC    16
#define DC    32
#define NCOL  512

__device__ __forceinline__ float bflo(u32 v){ return __uint_as_float(v << 16); }
__device__ __forceinline__ float bfhi(u32 v){ return __uint_as_float(v & 0xffff0000u); }
__device__ __forceinline__ u32 bfround(u32 ua){ return (ua + 0x7fffu + ((ua >> 16) & 1u)) >> 16; }
__device__ __forceinline__ u32 pack2(float a, float b){
    return (bfround(__float_as_uint(a)) & 0xffffu) | (bfround(__float_as_uint(b)) << 16);
}
__device__ __forceinline__ bf16x8 ldfrag(const u16* p){
    return __builtin_bit_cast(bf16x8, *(const uint4*)p);
}

// Swizzled address (bf16 units) for a [64][256] bf16 LDS tile.
// Verified (rounds 0-4) for 16B row-chunk writes/reads (d%8==0) and column u16 gathers.
__device__ __forceinline__ int lds_x(int r, int d){
    int sw = (d >> 2) ^ ((r & 7) << 1) ^ (((r >> 3) & 3) << 2);
    return r * 256 + (sw << 2) + (d & 3);
}

// K0: pure streaming cast. Per (b, 64-row chunk): x fp32 -> xb bf16 (8-deep
// load batching for latency), col-sums via LDS reduce (1 atomic/d/block).
// W -> Wb/WT in the jc==0 blocks.
__global__ __launch_bounds__(256) void k_pre(const float* __restrict__ x, const float* __restrict__ W,
                                             u16* __restrict__ xb, float* __restrict__ s,
                                             uint2* __restrict__ Wb, uint2* __restrict__ WT){
    __shared__ float csum[4][256];
    const int t = threadIdx.x, jc = blockIdx.x, b = blockIdx.y;

    if (jc == 0){   // W conversions: 128 (b) blocks cover all 32768 float4s of W
        int id = b * 256 + t;
        float4 w4 = ((const float4*)W)[id];
        Wb[id] = make_uint2(pack2(w4.x, w4.y), pack2(w4.z, w4.w));
        int c = id >> 6, d4 = id & 63;           // WT[c][4*d4 .. +3]
        float e0 = W[(size_t)(d4 * 4 + 0) * NCOL + c];
        float e1 = W[(size_t)(d4 * 4 + 1) * NCOL + c];
        float e2 = W[(size_t)(d4 * 4 + 2) * NCOL + c];
        float e3 = W[(size_t)(d4 * 4 + 3) * NCOL + c];
        WT[c * 64 + d4] = make_uint2(pack2(e0, e1), pack2(e2, e3));
    }
    const float4* xg = (const float4*)(x + ((size_t)b * NIN + jc * 64) * DIN);
    uint2* xbw = (uint2*)xb + ((size_t)(b * NIN + jc * 64)) * 64;   // 1 uint2 per float4
    float cs0 = 0.f, cs1 = 0.f, cs2 = 0.f, cs3 = 0.f;
    #pragma unroll
    for (int mb = 0; mb < 2; mb++){
        float4 v[8];
        #pragma unroll
        for (int m = 0; m < 8; m++) v[m] = xg[mb * 2048 + t + 256 * m];   // 8 loads in flight
        #pragma unroll
        for (int m = 0; m < 8; m++){
            uint2 p = make_uint2(pack2(v[m].x, v[m].y), pack2(v[m].z, v[m].w));
            xbw[mb * 2048 + t + 256 * m] = p;
            cs0 += bflo(p.x); cs1 += bfhi(p.x);
            cs2 += bflo(p.y); cs3 += bfhi(p.y);
        }
    }
    // thread's elements all share d4 = (t&63): reduce rows r ≡ t>>6 (mod 4)
    *(float4*)&csum[t >> 6][(t & 63) * 4] = make_float4(cs0, cs1, cs2, cs3);
    __syncthreads();
    {
        float acc = csum[0][t] + csum[1][t] + csum[2][t] + csum[3][t];
        atomicAdd(&s[b * DIN + t], acc);
    }
}

// K1: per (b, 64-row j-chunk), 512 threads / 8 waves, 44 KB LDS (3 blocks/CU):
//     stage bf16 tile once; bb = v.x^T (MFMA, row frags from LDS, ks split
//     across wave halves); softmax over i; z partial = c.x (MFMA, B-frag via
//     column u16 gather from the SAME tile); atomicAdd into zg.
__global__ __launch_bounds__(512) void k_main(const u16* __restrict__ xb, const u16* __restrict__ vb,
                                              float* __restrict__ zg){
    __shared__ __align__(16) u16 xt[64 * 256];    // 32 KB swizzled
    __shared__ float bbl[2][16][68];              //  8.5 KB (two ks-half partials)
    __shared__ __align__(16) u16 cl[16][80];      //  2.5 KB (160B pitch, 16B-aligned)
    const int t = threadIdx.x, jc = blockIdx.x, b = blockIdx.y;
    const int lane = t & 63, wv = t >> 6;
    const int l15 = lane & 15, q = lane >> 4;
    const int kh = wv >> 2, jt = wv & 3;          // ks-half, j-tile of this wave

    // stage 64x256 bf16 tile: 2048 uint4, coalesced loads, swizzled 16B writes
    uint4 st[4];
    {
        const uint4* xg = (const uint4*)(xb + ((size_t)(b * NIN + jc * 64)) * 256);
        #pragma unroll
        for (int m = 0; m < 4; m++) st[m] = xg[t + 512 * m];
    }
    // v A-fragments for this wave's ks-half: lane(l15,q) = v[i=l15][ks*32+q*8 .. +7]
    uint4 vf[4];
    #pragma unroll
    for (int e = 0; e < 4; e++)
        vf[e] = *(const uint4*)&vb[((size_t)b * 16 + l15) * 256 + (kh * 4 + e) * 32 + q * 8];
    #pragma unroll
    for (int m = 0; m < 4; m++){
        int id = t + 512 * m;                     // row = id>>5, col8 = id&31
        *(uint4*)&xt[lds_x(id >> 5, (id & 31) * 8)] = st[m];
    }
    __syncthreads();

    // phase A: bb partial [kh][i][j] — A = v frags, B = x row frags from LDS
    {
        f32x4 acc = {0.f, 0.f, 0.f, 0.f};
        #pragma unroll
        for (int e = 0; e < 4; e++)
            acc = __builtin_amdgcn_mfma_f32_16x16x32_bf16(
                __builtin_bit_cast(bf16x8, vf[e]),
                ldfrag(&xt[lds_x(jt * 16 + l15, (kh * 4 + e) * 32 + q * 8)]), acc, 0, 0, 0);
        #pragma unroll
        for (int r = 0; r < 4; r++) bbl[kh][q * 4 + r][jt * 16 + l15] = acc[r];  // row=i, col=j
    }
    __syncthreads();

    // phase B: softmax over i per column j (64 columns)
    if (t < 64){
        float mx = -1e30f, e[16], sum = 0.f;
        #pragma unroll
        for (int i = 0; i < 16; i++){
            float v = bbl[0][i][t] + bbl[1][i][t];
            bbl[0][i][t] = v;
            mx = fmaxf(mx, v);
        }
        #pragma unroll
        for (int i = 0; i < 16; i++){ e[i] = __expf(bbl[0][i][t] - mx); sum += e[i]; }
        float inv = 1.f / sum;
        #pragma unroll
        for (int i = 0; i < 16; i++) cl[i][t] = (u16)bfround(__float_as_uint(e[i] * inv));
    }
    __syncthreads();

    // phase C: z partial — A = c frags, B = x^T frags gathered from LDS tile
    bf16x8 cf[2];
    #pragma unroll
    for (int js = 0; js < 2; js++) cf[js] = ldfrag(&cl[l15][js * 32 + q * 8]);
    #pragma unroll
    for (int u = 0; u < 2; u++){
        int dt = wv * 2 + u;                      // 16 d-tiles / 8 waves
        f32x4 acc = {0.f, 0.f, 0.f, 0.f};
        #pragma unroll
        for (int js = 0; js < 2; js++){
            u32 w[4];
            #pragma unroll
            for (int e2 = 0; e2 < 4; e2++){
                u32 lo = xt[lds_x(js * 32 + q * 8 + 2 * e2,     dt * 16 + l15)];
                u32 hi = xt[lds_x(js * 32 + q * 8 + 2 * e2 + 1, dt * 16 + l15)];
                w[e2] = lo | (hi << 16);
            }
            acc = __builtin_amdgcn_mfma_f32_16x16x32_bf16(
                cf[js], __builtin_bit_cast(bf16x8, make_uint4(w[0], w[1], w[2], w[3])), acc, 0, 0, 0);
        }
        #pragma unroll
        for (int r = 0; r < 4; r++)
            atomicAdd(&zg[((size_t)b * 16 + q * 4 + r) * 256 + dt * 16 + l15], acc[r]);
    }
}

// K2: per (b, half): 8 capsules. y = z.W (zg read+zero), squash, v = o.W via WT.
__global__ __launch_bounds__(256) void k_tail(const float* __restrict__ s, float* __restrict__ zg,
                                              const u16* __restrict__ Wb, const u32* __restrict__ WT32,
                                              u16* __restrict__ vb, float* __restrict__ out, int mode){
    __shared__ float zl[8][260];
    __shared__ __align__(16) float ol[256];
    const int ih2 = blockIdx.x, b = blockIdx.y, t = threadIdx.x;
    const int i_loc = t >> 5;                     // 0..7
    const int o_idx = ih2 * 256 + t;              // global (i,k) flat index
    float y = 0.f;
    if (mode == 0){
        zl[0][t] = s[b * 256 + t] * (1.f / 16.f);
        __syncthreads();
        #pragma unroll 8
        for (int d = 0; d < 256; d++) y += zl[0][d] * bflo((u32)Wb[d * 512 + o_idx]);
    } else {
        #pragma unroll
        for (int u0 = 0; u0 < 8; u0++){
            int idx = t + 256 * u0;               // (ii, dd) over 8x256
            int ii = idx >> 8, dd = idx & 255;
            size_t a = ((size_t)b * 16 + ih2 * 8 + ii) * 256 + dd;
            float acc = zg[a];
            if (mode == 1) zg[a] = 0.f;           // ready for next iteration's atomics
            zl[ii][dd] = acc;
        }
        __syncthreads();
        #pragma unroll 8
        for (int d = 0; d < 256; d++) y += zl[i_loc][d] * bflo((u32)Wb[d * 512 + o_idx]);
    }
    // squash (unit-norm over the 32 k-lanes of each capsule)
    float s2 = y * y;
    s2 += __shfl_xor(s2, 1); s2 += __shfl_xor(s2, 2); s2 += __shfl_xor(s2, 4);
    s2 += __shfl_xor(s2, 8); s2 += __shfl_xor(s2, 16);
    float r = y / sqrtf(s2 + 1e-7f);
    if (mode == 2){ out[b * 512 + o_idx] = r; return; }
    ol[t] = r;
    __syncthreads();
    // v-pass: thread owns d-pair dh; 4 capsules of this half (coalesced WT reads)
    {
        int dh = t & 127, ihalf = t >> 7;
        #pragma unroll
        for (int e = 0; e < 4; e++){
            int ii = ihalf * 4 + e;
            int i2 = ih2 * 8 + ii;
            float a0 = 0.f, a1 = 0.f;
            #pragma unroll
            for (int k = 0; k < 32; k++){
                u32 wv2 = WT32[(size_t)(i2 * 32 + k) * 128 + dh];
                float ok = ol[ii * 32 + k];
                a0 += ok * bflo(wv2); a1 += ok * bfhi(wv2);
            }
            ((u32*)vb)[(size_t)(b * 16 + i2) * 128 + dh] = pack2(a0, a1);
        }
    }
}

extern "C" void kernel_launch(void* const* d_in, const int* in_sizes, int n_in,
                              void* d_out, int out_size, void* d_ws, size_t ws_size,
                              hipStream_t stream){
    const float* x = (const float*)d_in[0];    // fp32 [128][1024][256]
    const float* W = (const float*)d_in[1];    // fp32 [256][512]
    float* out = (float*)d_out;                // fp32 [128][16][32]
    char* ws = (char*)d_ws;                    // ~71 MB used (loop hot set L3-fits)
    float* s    = (float*)(ws);                //    131,072 B : column sums
    float* zg   = (float*)(ws + 131072);       //  2,097,152 B : z accumulator [128][16][256]
    u16*   Wb   = (u16*)  (ws + 2228224);      //    262,144 B : W bf16 [d][c]
    u32*   WT   = (u32*)  (ws + 2490368);      //    262,144 B : W^T bf16 [c][d]
    u16*   vb   = (u16*)  (ws + 2752512);      //  1,048,576 B : v = o.W-slices, bf16
    u16*   xb   = (u16*)  (ws + 3801088);      // 67,108,864 B : x bf16 row-major

    hipMemsetAsync(ws, 0, 2228224, stream);    // s + zg
    k_pre<<<dim3(16, BATCH), 256, 0, stream>>>(x, W, xb, s, (uint2*)Wb, (uint2*)WT);
    k_tail<<<dim3(2, BATCH), 256, 0, stream>>>(s, zg, Wb, WT, vb, out, 0);
    for (int it = 1; it < 4; it++){
        k_main<<<dim3(16, BATCH), 512, 0, stream>>>(xb, vb, zg);
        k_tail<<<dim3(2, BATCH), 256, 0, stream>>>(s, zg, Wb, WT, vb, out, it == 3 ? 2 : 1);
    }
}